// Round 7
// baseline (152.676 us; speedup 1.0000x reference)
//
#include <hip/hip_runtime.h>
#include <math.h>

#define BSZ 4096
#define DIM 256
// 20 * log2(e): rows are pre-scaled by sqrt(20*log2e)/||row|| so the MFMA
// emits u = score*log2e; exp2(u - SC20L2E) == exp(score - 20) exactly.
#define SC20L2E 28.853900817779268f

#if __has_builtin(__builtin_amdgcn_exp2f)
#define EXP2F(x) __builtin_amdgcn_exp2f(x)
#else
#define EXP2F(x) exp2f(x)
#endif

typedef float floatx4 __attribute__((ext_vector_type(4)));

__device__ __forceinline__ void async_cp16(void* lds, const void* g) {
    __builtin_amdgcn_global_load_lds(
        (__attribute__((address_space(1))) unsigned int*)(unsigned long long)g,
        (__attribute__((address_space(3))) unsigned int*)lds,
        16, 0, 0);
}

// One wave per row index: load row r of all 4 matrices once.
// Outputs: fp8 e4m3 rows pre-scaled by sqrt(20*log2e)/||row||, fp32 diagonal
// scores for the 4 pairs; zeroes rowsum/colsum; inits out[0]=40 (const term).
__global__ __launch_bounds__(256)
void prep_kernel(const float* __restrict__ a0, const float* __restrict__ a1,
                 const float* __restrict__ a2, const float* __restrict__ a3,
                 unsigned char* __restrict__ f8, float* __restrict__ diag,
                 float* __restrict__ rowsum, float* __restrict__ colsum,
                 float* __restrict__ out) {
    const float* srcs[4] = {a0, a1, a2, a3};
    int w = threadIdx.x >> 6, lane = threadIdx.x & 63;
    int row = blockIdx.x * 4 + w;

    float4 v[4];
    float red[8];
    #pragma unroll
    for (int m = 0; m < 4; m++) {
        v[m] = ((const float4*)(srcs[m] + (size_t)row * DIM))[lane];
        red[m] = v[m].x * v[m].x + v[m].y * v[m].y + v[m].z * v[m].z + v[m].w * v[m].w;
    }
    // pair dots: (0,1) (0,2) (1,2) (1,3)
    red[4] = v[0].x * v[1].x + v[0].y * v[1].y + v[0].z * v[1].z + v[0].w * v[1].w;
    red[5] = v[0].x * v[2].x + v[0].y * v[2].y + v[0].z * v[2].z + v[0].w * v[2].w;
    red[6] = v[1].x * v[2].x + v[1].y * v[2].y + v[1].z * v[2].z + v[1].w * v[2].w;
    red[7] = v[1].x * v[3].x + v[1].y * v[3].y + v[1].z * v[3].z + v[1].w * v[3].w;

    #pragma unroll
    for (int i = 0; i < 8; i++) {
        #pragma unroll
        for (int s = 32; s; s >>= 1) red[i] += __shfl_xor(red[i], s, 64);
    }

    float rinv[4];
    #pragma unroll
    for (int m = 0; m < 4; m++) rinv[m] = rsqrtf(fmaxf(red[m], 1e-24f));

    const float sq = sqrtf(SC20L2E);
    #pragma unroll
    for (int m = 0; m < 4; m++) {
        float sc = sq * rinv[m];
        int pk = __builtin_amdgcn_cvt_pk_fp8_f32(v[m].x * sc, v[m].y * sc, 0, false);
        pk = __builtin_amdgcn_cvt_pk_fp8_f32(v[m].z * sc, v[m].w * sc, pk, true);
        ((unsigned int*)(f8 + (size_t)m * BSZ * DIM))[row * 64 + lane] = (unsigned int)pk;
    }

    if (lane == 0) {
        diag[0 * BSZ + row] = red[4] * 20.0f * rinv[0] * rinv[1];
        diag[1 * BSZ + row] = red[5] * 20.0f * rinv[0] * rinv[2];
        diag[2 * BSZ + row] = red[6] * 20.0f * rinv[1] * rinv[2];
        diag[3 * BSZ + row] = red[7] * 20.0f * rinv[1] * rinv[3];
    }
    if (blockIdx.x < 64) {
        int idx = blockIdx.x * 256 + threadIdx.x;
        rowsum[idx] = 0.f;
        colsum[idx] = 0.f;
        if (idx == 0) out[0] = 40.0f;   // + 20*4B/(2B) constant term
    }
}

// 128x128 tile of exp(score-20) per block (pair = blockIdx.z), fp8 MFMA.
// K split in two 128-wide phases: 32 KB LDS/block -> 5 blocks/CU.
// XOR chunk swizzle over 8 chunks/row: chunk(row,kq) at row*128 +
// (((kq^row)&7)<<4); fragment address = Q ^ (ks<<5), Q hoisted.
// Accumulators init to -SC20L2E so the epilogue is a bare v_exp_f32.
__global__ __launch_bounds__(256, 5)
void pair_scores_kernel(const unsigned char* __restrict__ f8,
                        float* __restrict__ rowsum,
                        float* __restrict__ colsum) {
    const int PX[4] = {0, 0, 1, 1};
    const int PY[4] = {1, 2, 2, 3};
    int p = blockIdx.z;
    const unsigned char* Xb = f8 + (size_t)PX[p] * BSZ * DIM;
    const unsigned char* Yb = f8 + (size_t)PY[p] * BSZ * DIM;
    float* rs = rowsum + p * BSZ;
    float* cs = colsum + p * BSZ;

    __shared__ __align__(16) unsigned char smem[32768];

    int tid  = threadIdx.x;
    int lane = tid & 63;
    int w    = tid >> 6;
    int wm = w >> 1, wn = w & 1;
    int q = lane >> 4, l = lane & 15;
    int bi = blockIdx.x * 128, bj = blockIdx.y * 128;

    // Hoisted fragment bases: Q = row*128 + qb + (((qh^row)&7)<<4)
    int qh = q >> 1, qb = (q & 1) * 8;
    unsigned qa[4], qbv[4];
    #pragma unroll
    for (int t = 0; t < 4; t++) {
        int ra = wm * 64 + t * 16 + l;
        int rb = wn * 64 + t * 16 + l;
        qa[t]  = (unsigned)(ra * 128 + qb + (((qh ^ ra) & 7) << 4));
        qbv[t] = (unsigned)(16384 + rb * 128 + qb + (((qh ^ rb) & 7) << 4));
    }

    // Staging addresses (computed once; phase 1 adds +128 B on the k axis).
    const unsigned char* gA[4];
    const unsigned char* gB[4];
    unsigned ldsoff[4];
    #pragma unroll
    for (int i = 0; i < 4; i++) {
        int sb  = i * 256 + w * 64;     // wave-uniform chunk base
        int s   = sb + lane;
        int row = s >> 3;
        int kq  = (s ^ row) & 7;
        ldsoff[i] = (unsigned)(sb * 16);
        gA[i] = Xb + (size_t)(bi + row) * 256 + kq * 16;
        gB[i] = Yb + (size_t)(bj + row) * 256 + kq * 16;
    }

    floatx4 acc[4][4];
    #pragma unroll
    for (int i = 0; i < 4; i++)
        #pragma unroll
        for (int j = 0; j < 4; j++)
            acc[i][j] = (floatx4){-SC20L2E, -SC20L2E, -SC20L2E, -SC20L2E};

    #pragma unroll
    for (int ph = 0; ph < 2; ph++) {
        if (ph) __syncthreads();        // phase-0 reads complete
        int ko = ph * 128;
        #pragma unroll
        for (int i = 0; i < 4; i++) {
            async_cp16(smem + ldsoff[i],         gA[i] + ko);
            async_cp16(smem + 16384 + ldsoff[i], gB[i] + ko);
        }
        __syncthreads();                // staging drained (vmcnt in barrier)

        #pragma unroll
        for (int ks = 0; ks < 4; ks++) {
            const unsigned kx = (unsigned)(ks << 5);
            long long a[4], b[4];
            #pragma unroll
            for (int t = 0; t < 4; t++) {
                a[t] = *(const long long*)(smem + (qa[t] ^ kx));
                b[t] = *(const long long*)(smem + (qbv[t] ^ kx));
            }
            #pragma unroll
            for (int i = 0; i < 4; i++)
                #pragma unroll
                for (int j = 0; j < 4; j++)
                    acc[i][j] = __builtin_amdgcn_mfma_f32_16x16x32_fp8_fp8(a[i], b[j], acc[i][j], 0, 0, 0);
        }
    }

    // ---- epilogue: exp2 (raw v_exp_f32), butterfly reductions, atomics ----
    // C/D layout per 16x16 tile: col = l, row = q*4 + reg.
    #pragma unroll
    for (int ai = 0; ai < 4; ai++)
        #pragma unroll
        for (int bt = 0; bt < 4; bt++)
            #pragma unroll
            for (int r = 0; r < 4; r++)
                acc[ai][bt][r] = EXP2F(acc[ai][bt][r]);

    // Row sums: v[t], t = ai*4+r, reduce over the 16 l-lanes; result t -> lane l==t.
    float v[16];
    #pragma unroll
    for (int ai = 0; ai < 4; ai++)
        #pragma unroll
        for (int r = 0; r < 4; r++)
            v[ai * 4 + r] = acc[ai][0][r] + acc[ai][1][r] + acc[ai][2][r] + acc[ai][3][r];

    float w1[8];
    #pragma unroll
    for (int k = 0; k < 8; k++) {
        float snd = (l & 1) ? v[2 * k] : v[2 * k + 1];
        float got = __shfl_xor(snd, 1, 64);
        w1[k] = ((l & 1) ? v[2 * k + 1] : v[2 * k]) + got;
    }
    float w2[4];
    #pragma unroll
    for (int m = 0; m < 4; m++) {
        float snd = ((l >> 1) & 1) ? w1[2 * m] : w1[2 * m + 1];
        float got = __shfl_xor(snd, 2, 64);
        w2[m] = (((l >> 1) & 1) ? w1[2 * m + 1] : w1[2 * m]) + got;
    }
    float w3[2];
    #pragma unroll
    for (int n = 0; n < 2; n++) {
        float snd = ((l >> 2) & 1) ? w2[2 * n] : w2[2 * n + 1];
        float got = __shfl_xor(snd, 4, 64);
        w3[n] = (((l >> 2) & 1) ? w2[2 * n + 1] : w2[2 * n]) + got;
    }
    {
        float snd = ((l >> 3) & 1) ? w3[0] : w3[1];
        float got = __shfl_xor(snd, 8, 64);
        float wr = (((l >> 3) & 1) ? w3[1] : w3[0]) + got;
        atomicAdd(&rs[bi + wm * 64 + ((l >> 2) << 4) + q * 4 + (l & 3)], wr);
    }

    // Col sums: c4[bt], reduce over the 4 q-groups; result bt -> q==bt.
    float c4[4];
    #pragma unroll
    for (int bt = 0; bt < 4; bt++) {
        float s = 0.f;
        #pragma unroll
        for (int ai = 0; ai < 4; ai++)
            #pragma unroll
            for (int r = 0; r < 4; r++) s += acc[ai][bt][r];
        c4[bt] = s;
    }
    float e0, e1, fsum;
    {
        float snd = (q & 1) ? c4[0] : c4[1];
        float got = __shfl_xor(snd, 16, 64);
        e0 = ((q & 1) ? c4[1] : c4[0]) + got;
    }
    {
        float snd = (q & 1) ? c4[2] : c4[3];
        float got = __shfl_xor(snd, 16, 64);
        e1 = ((q & 1) ? c4[3] : c4[2]) + got;
    }
    {
        float snd = ((q >> 1) & 1) ? e0 : e1;
        float got = __shfl_xor(snd, 32, 64);
        fsum = (((q >> 1) & 1) ? e1 : e0) + got;
    }
    atomicAdd(&cs[bj + wn * 64 + (q << 4) + l], fsum);
}

// 64 blocks: each thread one (pair,row) entry; wave-reduce then atomicAdd
// into out (prep pre-set out = 40, the 20*4B/(2B) constant).
__global__ __launch_bounds__(256)
void final_reduce_kernel(const float* __restrict__ rowsum,
                         const float* __restrict__ colsum,
                         const float* __restrict__ diag,
                         float* __restrict__ out) {
    int idx = blockIdx.x * 256 + threadIdx.x;
    float acc = 0.5f * (__logf(rowsum[idx]) + __logf(colsum[idx])) - diag[idx];
    #pragma unroll
    for (int s = 32; s; s >>= 1) acc += __shfl_xor(acc, s, 64);
    if ((threadIdx.x & 63) == 0)
        atomicAdd(out, acc * (1.0f / (2.0f * BSZ)));
}

extern "C" void kernel_launch(void* const* d_in, const int* in_sizes, int n_in,
                              void* d_out, int out_size, void* d_ws, size_t ws_size,
                              hipStream_t stream) {
    const float* in_anchor = (const float*)d_in[0];
    const float* in_pos    = (const float*)d_in[1];
    // d_in[2] (reference_anchor) intentionally unused, matching the reference.
    const float* in_rtext  = (const float*)d_in[3];
    const float* in_rvis   = (const float*)d_in[4];

    char* ws = (char*)d_ws;
    unsigned char* f8 = (unsigned char*)ws;                 // 4 * B * D fp8
    size_t f8_bytes = (size_t)4 * BSZ * DIM;
    float* rowsum = (float*)(ws + f8_bytes);                // 4 * B
    float* colsum = rowsum + 4 * BSZ;                       // 4 * B
    float* diag   = colsum + 4 * BSZ;                       // 4 * B

    prep_kernel<<<BSZ / 4, 256, 0, stream>>>(
        in_anchor, in_pos, in_rtext, in_rvis, f8, diag, rowsum, colsum,
        (float*)d_out);

    pair_scores_kernel<<<dim3(BSZ / 128, BSZ / 128, 4), 256, 0, stream>>>(
        f8, rowsum, colsum);

    final_reduce_kernel<<<64, 256, 0, stream>>>(
        rowsum, colsum, diag, (float*)d_out);
}

// Round 8
// 106.337 us; speedup vs baseline: 1.4358x; 1.4358x over previous
//
#include <hip/hip_runtime.h>
#include <math.h>

#define BSZ 4096
#define DIM 256
// 20 * log2(e): rows are pre-scaled by sqrt(20*log2e)/||row|| so the MFMA
// emits u = score*log2e; exp2(u - SC20L2E) == exp(score - 20) exactly.
#define SC20L2E 28.853900817779268f

#if __has_builtin(__builtin_amdgcn_exp2f)
#define EXP2F(x) __builtin_amdgcn_exp2f(x)
#else
#define EXP2F(x) exp2f(x)
#endif

typedef float floatx4 __attribute__((ext_vector_type(4)));

__device__ __forceinline__ void async_cp16(void* lds, const void* g) {
    __builtin_amdgcn_global_load_lds(
        (__attribute__((address_space(1))) unsigned int*)(unsigned long long)g,
        (__attribute__((address_space(3))) unsigned int*)lds,
        16, 0, 0);
}

// One wave per row index: load row r of all 4 matrices once.
// Outputs: fp8 e4m3 rows pre-scaled by sqrt(20*log2e)/||row||, fp32 diagonal
// scores for the 4 pairs; zeroes rowsum/colsum; inits out[0]=40 (const term).
__global__ __launch_bounds__(256)
void prep_kernel(const float* __restrict__ a0, const float* __restrict__ a1,
                 const float* __restrict__ a2, const float* __restrict__ a3,
                 unsigned char* __restrict__ f8, float* __restrict__ diag,
                 float* __restrict__ rowsum, float* __restrict__ colsum,
                 float* __restrict__ out) {
    const float* srcs[4] = {a0, a1, a2, a3};
    int w = threadIdx.x >> 6, lane = threadIdx.x & 63;
    int row = blockIdx.x * 4 + w;

    float4 v[4];
    float red[8];
    #pragma unroll
    for (int m = 0; m < 4; m++) {
        v[m] = ((const float4*)(srcs[m] + (size_t)row * DIM))[lane];
        red[m] = v[m].x * v[m].x + v[m].y * v[m].y + v[m].z * v[m].z + v[m].w * v[m].w;
    }
    // pair dots: (0,1) (0,2) (1,2) (1,3)
    red[4] = v[0].x * v[1].x + v[0].y * v[1].y + v[0].z * v[1].z + v[0].w * v[1].w;
    red[5] = v[0].x * v[2].x + v[0].y * v[2].y + v[0].z * v[2].z + v[0].w * v[2].w;
    red[6] = v[1].x * v[2].x + v[1].y * v[2].y + v[1].z * v[2].z + v[1].w * v[2].w;
    red[7] = v[1].x * v[3].x + v[1].y * v[3].y + v[1].z * v[3].z + v[1].w * v[3].w;

    #pragma unroll
    for (int i = 0; i < 8; i++) {
        #pragma unroll
        for (int s = 32; s; s >>= 1) red[i] += __shfl_xor(red[i], s, 64);
    }

    float rinv[4];
    #pragma unroll
    for (int m = 0; m < 4; m++) rinv[m] = rsqrtf(fmaxf(red[m], 1e-24f));

    const float sq = sqrtf(SC20L2E);
    #pragma unroll
    for (int m = 0; m < 4; m++) {
        float sc = sq * rinv[m];
        int pk = __builtin_amdgcn_cvt_pk_fp8_f32(v[m].x * sc, v[m].y * sc, 0, false);
        pk = __builtin_amdgcn_cvt_pk_fp8_f32(v[m].z * sc, v[m].w * sc, pk, true);
        ((unsigned int*)(f8 + (size_t)m * BSZ * DIM))[row * 64 + lane] = (unsigned int)pk;
    }

    if (lane == 0) {
        diag[0 * BSZ + row] = red[4] * 20.0f * rinv[0] * rinv[1];
        diag[1 * BSZ + row] = red[5] * 20.0f * rinv[0] * rinv[2];
        diag[2 * BSZ + row] = red[6] * 20.0f * rinv[1] * rinv[2];
        diag[3 * BSZ + row] = red[7] * 20.0f * rinv[1] * rinv[3];
    }
    if (blockIdx.x < 64) {
        int idx = blockIdx.x * 256 + threadIdx.x;
        rowsum[idx] = 0.f;
        colsum[idx] = 0.f;
        if (idx == 0) out[0] = 40.0f;   // + 20*4B/(2B) constant term
    }
}

// 128x128 tile of exp(score-20) per block (pair = blockIdx.z), fp8 MFMA.
// K split in two 128-wide phases: 32 KB LDS/block.
// __launch_bounds__(256,4): 128-VGPR budget -> no accumulator spill (the
// round-7 (256,5) variant spilled acc to scratch: 48 VGPR, 192 MB writes).
// 4 blocks/CU (VGPR-capped; LDS would allow 5).
// XOR chunk swizzle over 8 chunks/row: chunk(row,kq) at row*128 +
// (((kq^row)&7)<<4); fragment address = Q ^ (ks<<5), Q hoisted.
// Accumulators init to -SC20L2E so the epilogue is a bare v_exp_f32.
__global__ __launch_bounds__(256, 4)
void pair_scores_kernel(const unsigned char* __restrict__ f8,
                        float* __restrict__ rowsum,
                        float* __restrict__ colsum) {
    const int PX[4] = {0, 0, 1, 1};
    const int PY[4] = {1, 2, 2, 3};
    int p = blockIdx.z;
    const unsigned char* Xb = f8 + (size_t)PX[p] * BSZ * DIM;
    const unsigned char* Yb = f8 + (size_t)PY[p] * BSZ * DIM;
    float* rs = rowsum + p * BSZ;
    float* cs = colsum + p * BSZ;

    __shared__ __align__(16) unsigned char smem[32768];

    int tid  = threadIdx.x;
    int lane = tid & 63;
    int w    = tid >> 6;
    int wm = w >> 1, wn = w & 1;
    int q = lane >> 4, l = lane & 15;
    int bi = blockIdx.x * 128, bj = blockIdx.y * 128;

    // Hoisted fragment bases: Q = row*128 + qb + (((qh^row)&7)<<4)
    int qh = q >> 1, qb = (q & 1) * 8;
    unsigned qa[4], qbv[4];
    #pragma unroll
    for (int t = 0; t < 4; t++) {
        int ra = wm * 64 + t * 16 + l;
        int rb = wn * 64 + t * 16 + l;
        qa[t]  = (unsigned)(ra * 128 + qb + (((qh ^ ra) & 7) << 4));
        qbv[t] = (unsigned)(16384 + rb * 128 + qb + (((qh ^ rb) & 7) << 4));
    }

    // Staging addresses (computed once; phase 1 adds +128 B on the k axis).
    const unsigned char* gA[4];
    const unsigned char* gB[4];
    unsigned ldsoff[4];
    #pragma unroll
    for (int i = 0; i < 4; i++) {
        int sb  = i * 256 + w * 64;     // wave-uniform chunk base
        int s   = sb + lane;
        int row = s >> 3;
        int kq  = (s ^ row) & 7;
        ldsoff[i] = (unsigned)(sb * 16);
        gA[i] = Xb + (size_t)(bi + row) * 256 + kq * 16;
        gB[i] = Yb + (size_t)(bj + row) * 256 + kq * 16;
    }

    floatx4 acc[4][4];
    #pragma unroll
    for (int i = 0; i < 4; i++)
        #pragma unroll
        for (int j = 0; j < 4; j++)
            acc[i][j] = (floatx4){-SC20L2E, -SC20L2E, -SC20L2E, -SC20L2E};

    #pragma unroll
    for (int ph = 0; ph < 2; ph++) {
        if (ph) __syncthreads();        // phase-0 reads complete
        int ko = ph * 128;
        #pragma unroll
        for (int i = 0; i < 4; i++) {
            async_cp16(smem + ldsoff[i],         gA[i] + ko);
            async_cp16(smem + 16384 + ldsoff[i], gB[i] + ko);
        }
        __syncthreads();                // staging drained (vmcnt in barrier)

        #pragma unroll
        for (int ks = 0; ks < 4; ks++) {
            const unsigned kx = (unsigned)(ks << 5);
            long long a[4], b[4];
            #pragma unroll
            for (int t = 0; t < 4; t++) {
                a[t] = *(const long long*)(smem + (qa[t] ^ kx));
                b[t] = *(const long long*)(smem + (qbv[t] ^ kx));
            }
            #pragma unroll
            for (int i = 0; i < 4; i++)
                #pragma unroll
                for (int j = 0; j < 4; j++)
                    acc[i][j] = __builtin_amdgcn_mfma_f32_16x16x32_fp8_fp8(a[i], b[j], acc[i][j], 0, 0, 0);
        }
    }

    // ---- epilogue: exp2 (raw v_exp_f32), butterfly reductions, atomics ----
    // C/D layout per 16x16 tile: col = l, row = q*4 + reg.
    #pragma unroll
    for (int ai = 0; ai < 4; ai++)
        #pragma unroll
        for (int bt = 0; bt < 4; bt++)
            #pragma unroll
            for (int r = 0; r < 4; r++)
                acc[ai][bt][r] = EXP2F(acc[ai][bt][r]);

    // Row sums: v[t], t = ai*4+r, reduce over the 16 l-lanes; result t -> lane l==t.
    float v[16];
    #pragma unroll
    for (int ai = 0; ai < 4; ai++)
        #pragma unroll
        for (int r = 0; r < 4; r++)
            v[ai * 4 + r] = acc[ai][0][r] + acc[ai][1][r] + acc[ai][2][r] + acc[ai][3][r];

    float w1[8];
    #pragma unroll
    for (int k = 0; k < 8; k++) {
        float snd = (l & 1) ? v[2 * k] : v[2 * k + 1];
        float got = __shfl_xor(snd, 1, 64);
        w1[k] = ((l & 1) ? v[2 * k + 1] : v[2 * k]) + got;
    }
    float w2[4];
    #pragma unroll
    for (int m = 0; m < 4; m++) {
        float snd = ((l >> 1) & 1) ? w1[2 * m] : w1[2 * m + 1];
        float got = __shfl_xor(snd, 2, 64);
        w2[m] = (((l >> 1) & 1) ? w1[2 * m + 1] : w1[2 * m]) + got;
    }
    float w3[2];
    #pragma unroll
    for (int n = 0; n < 2; n++) {
        float snd = ((l >> 2) & 1) ? w2[2 * n] : w2[2 * n + 1];
        float got = __shfl_xor(snd, 4, 64);
        w3[n] = (((l >> 2) & 1) ? w2[2 * n + 1] : w2[2 * n]) + got;
    }
    {
        float snd = ((l >> 3) & 1) ? w3[0] : w3[1];
        float got = __shfl_xor(snd, 8, 64);
        float wr = (((l >> 3) & 1) ? w3[1] : w3[0]) + got;
        atomicAdd(&rs[bi + wm * 64 + ((l >> 2) << 4) + q * 4 + (l & 3)], wr);
    }

    // Col sums: c4[bt], reduce over the 4 q-groups; result bt -> q==bt.
    float c4[4];
    #pragma unroll
    for (int bt = 0; bt < 4; bt++) {
        float s = 0.f;
        #pragma unroll
        for (int ai = 0; ai < 4; ai++)
            #pragma unroll
            for (int r = 0; r < 4; r++) s += acc[ai][bt][r];
        c4[bt] = s;
    }
    float e0, e1, fsum;
    {
        float snd = (q & 1) ? c4[0] : c4[1];
        float got = __shfl_xor(snd, 16, 64);
        e0 = ((q & 1) ? c4[1] : c4[0]) + got;
    }
    {
        float snd = (q & 1) ? c4[2] : c4[3];
        float got = __shfl_xor(snd, 16, 64);
        e1 = ((q & 1) ? c4[3] : c4[2]) + got;
    }
    {
        float snd = ((q >> 1) & 1) ? e0 : e1;
        float got = __shfl_xor(snd, 32, 64);
        fsum = (((q >> 1) & 1) ? e1 : e0) + got;
    }
    atomicAdd(&cs[bj + wn * 64 + (q << 4) + l], fsum);
}

// 64 blocks: each thread one (pair,row) entry; wave-reduce then atomicAdd
// into out (prep pre-set out = 40, the 20*4B/(2B) constant).
__global__ __launch_bounds__(256)
void final_reduce_kernel(const float* __restrict__ rowsum,
                         const float* __restrict__ colsum,
                         const float* __restrict__ diag,
                         float* __restrict__ out) {
    int idx = blockIdx.x * 256 + threadIdx.x;
    float acc = 0.5f * (__logf(rowsum[idx]) + __logf(colsum[idx])) - diag[idx];
    #pragma unroll
    for (int s = 32; s; s >>= 1) acc += __shfl_xor(acc, s, 64);
    if ((threadIdx.x & 63) == 0)
        atomicAdd(out, acc * (1.0f / (2.0f * BSZ)));
}

extern "C" void kernel_launch(void* const* d_in, const int* in_sizes, int n_in,
                              void* d_out, int out_size, void* d_ws, size_t ws_size,
                              hipStream_t stream) {
    const float* in_anchor = (const float*)d_in[0];
    const float* in_pos    = (const float*)d_in[1];
    // d_in[2] (reference_anchor) intentionally unused, matching the reference.
    const float* in_rtext  = (const float*)d_in[3];
    const float* in_rvis   = (const float*)d_in[4];

    char* ws = (char*)d_ws;
    unsigned char* f8 = (unsigned char*)ws;                 // 4 * B * D fp8
    size_t f8_bytes = (size_t)4 * BSZ * DIM;
    float* rowsum = (float*)(ws + f8_bytes);                // 4 * B
    float* colsum = rowsum + 4 * BSZ;                       // 4 * B
    float* diag   = colsum + 4 * BSZ;                       // 4 * B

    prep_kernel<<<BSZ / 4, 256, 0, stream>>>(
        in_anchor, in_pos, in_rtext, in_rvis, f8, diag, rowsum, colsum,
        (float*)d_out);

    pair_scores_kernel<<<dim3(BSZ / 128, BSZ / 128, 4), 256, 0, stream>>>(
        f8, rowsum, colsum);

    final_reduce_kernel<<<64, 256, 0, stream>>>(
        rowsum, colsum, diag, (float*)d_out);
}

// Round 9
// 105.246 us; speedup vs baseline: 1.4507x; 1.0104x over previous
//
#include <hip/hip_runtime.h>
#include <math.h>

#define BSZ 4096
#define DIM 256
// 20 * log2(e): rows are pre-scaled by sqrt(20*log2e)/||row|| so the MFMA
// emits u = score*log2e; exp2(u - SC20L2E) == exp(score - 20) exactly.
#define SC20L2E 28.853900817779268f

#if __has_builtin(__builtin_amdgcn_exp2f)
#define EXP2F(x) __builtin_amdgcn_exp2f(x)
#else
#define EXP2F(x) exp2f(x)
#endif

typedef int   intx4    __attribute__((ext_vector_type(4)));
typedef int   intx8    __attribute__((ext_vector_type(8)));
typedef float floatx16 __attribute__((ext_vector_type(16)));

__device__ __forceinline__ void async_cp16(void* lds, const void* g) {
    __builtin_amdgcn_global_load_lds(
        (__attribute__((address_space(1))) unsigned int*)(unsigned long long)g,
        (__attribute__((address_space(3))) unsigned int*)lds,
        16, 0, 0);
}

// One wave per row index: load row r of all 4 matrices once.
// Outputs: fp8 e4m3 rows pre-scaled by sqrt(20*log2e)/||row||, fp32 diagonal
// scores for the 4 pairs; zeroes rowsum/colsum; inits out[0]=40 (const term).
__global__ __launch_bounds__(256)
void prep_kernel(const float* __restrict__ a0, const float* __restrict__ a1,
                 const float* __restrict__ a2, const float* __restrict__ a3,
                 unsigned char* __restrict__ f8, float* __restrict__ diag,
                 float* __restrict__ rowsum, float* __restrict__ colsum,
                 float* __restrict__ out) {
    const float* srcs[4] = {a0, a1, a2, a3};
    int w = threadIdx.x >> 6, lane = threadIdx.x & 63;
    int row = blockIdx.x * 4 + w;

    float4 v[4];
    float red[8];
    #pragma unroll
    for (int m = 0; m < 4; m++) {
        v[m] = ((const float4*)(srcs[m] + (size_t)row * DIM))[lane];
        red[m] = v[m].x * v[m].x + v[m].y * v[m].y + v[m].z * v[m].z + v[m].w * v[m].w;
    }
    // pair dots: (0,1) (0,2) (1,2) (1,3)
    red[4] = v[0].x * v[1].x + v[0].y * v[1].y + v[0].z * v[1].z + v[0].w * v[1].w;
    red[5] = v[0].x * v[2].x + v[0].y * v[2].y + v[0].z * v[2].z + v[0].w * v[2].w;
    red[6] = v[1].x * v[2].x + v[1].y * v[2].y + v[1].z * v[2].z + v[1].w * v[2].w;
    red[7] = v[1].x * v[3].x + v[1].y * v[3].y + v[1].z * v[3].z + v[1].w * v[3].w;

    #pragma unroll
    for (int i = 0; i < 8; i++) {
        #pragma unroll
        for (int s = 32; s; s >>= 1) red[i] += __shfl_xor(red[i], s, 64);
    }

    float rinv[4];
    #pragma unroll
    for (int m = 0; m < 4; m++) rinv[m] = rsqrtf(fmaxf(red[m], 1e-24f));

    const float sq = sqrtf(SC20L2E);
    #pragma unroll
    for (int m = 0; m < 4; m++) {
        float sc = sq * rinv[m];
        int pk = __builtin_amdgcn_cvt_pk_fp8_f32(v[m].x * sc, v[m].y * sc, 0, false);
        pk = __builtin_amdgcn_cvt_pk_fp8_f32(v[m].z * sc, v[m].w * sc, pk, true);
        ((unsigned int*)(f8 + (size_t)m * BSZ * DIM))[row * 64 + lane] = (unsigned int)pk;
    }

    if (lane == 0) {
        diag[0 * BSZ + row] = red[4] * 20.0f * rinv[0] * rinv[1];
        diag[1 * BSZ + row] = red[5] * 20.0f * rinv[0] * rinv[2];
        diag[2 * BSZ + row] = red[6] * 20.0f * rinv[1] * rinv[2];
        diag[3 * BSZ + row] = red[7] * 20.0f * rinv[1] * rinv[3];
    }
    if (blockIdx.x < 64) {
        int idx = blockIdx.x * 256 + threadIdx.x;
        rowsum[idx] = 0.f;
        colsum[idx] = 0.f;
        if (idx == 0) out[0] = 40.0f;   // + 20*4B/(2B) constant term
    }
}

// 128x128 tile of exp(score-20) per block (pair = blockIdx.z).
// MX-scaled fp8 MFMA (mfma_scale_f32_32x32x64_f8f6f4, unit E8M0 scales
// 0x7F = 2^0) -> 2.1x the non-scaled fp8 MFMA rate; numerics identical.
// K split in two 128-wide phases: 32 KB LDS/block, 4 blocks/CU at (256,4).
// XOR chunk swizzle over 8 chunks/row: slot(row,c) = row*8 + ((c^row)&7);
// fragment addr = Q ^ (ks<<6) ^ (j<<4), Q hoisted per (tile,lane).
// A/B operand layout (32x32x64): row = lane&31, k = (lane>>5)*32 + byte.
// C/D layout (32x32): col = lane&31, row = (reg&3)+8*(reg>>2)+4*(lane>>5).
// Accumulators init to -SC20L2E so the epilogue is a bare v_exp_f32.
__global__ __launch_bounds__(256, 4)
void pair_scores_kernel(const unsigned char* __restrict__ f8,
                        float* __restrict__ rowsum,
                        float* __restrict__ colsum) {
    const int PX[4] = {0, 0, 1, 1};
    const int PY[4] = {1, 2, 2, 3};
    int p = blockIdx.z;
    const unsigned char* Xb = f8 + (size_t)PX[p] * BSZ * DIM;
    const unsigned char* Yb = f8 + (size_t)PY[p] * BSZ * DIM;
    float* rs = rowsum + p * BSZ;
    float* cs = colsum + p * BSZ;

    __shared__ __align__(16) unsigned char smem[32768];

    int tid  = threadIdx.x;
    int lane = tid & 63;
    int w    = tid >> 6;
    int wm = w >> 1, wn = w & 1;
    int l5 = lane & 31, h = lane >> 5;
    int bi = blockIdx.x * 128, bj = blockIdx.y * 128;

    // Hoisted fragment bases: addr = row*128 + ((row&7)<<4), then XOR the
    // k-chunk bits (h<<5 folded here; ks<<6 and j<<4 at read time).
    unsigned qa[2], qb2[2];
    #pragma unroll
    for (int t = 0; t < 2; t++) {
        int ra = wm * 64 + t * 32 + l5;
        int rb = wn * 64 + t * 32 + l5;
        qa[t]  = (unsigned)(ra * 128 + ((ra & 7) << 4)) ^ (unsigned)(h << 5);
        qb2[t] = (unsigned)(16384 + rb * 128 + ((rb & 7) << 4)) ^ (unsigned)(h << 5);
    }

    // Staging addresses (16 KB per panel per phase; phase 1 adds +128 B).
    const unsigned char* gA[4];
    const unsigned char* gB[4];
    unsigned ldsoff[4];
    #pragma unroll
    for (int i = 0; i < 4; i++) {
        int sb  = i * 256 + w * 64;     // wave-uniform chunk base
        int s   = sb + lane;
        int row = s >> 3;
        int kq  = (s ^ row) & 7;
        ldsoff[i] = (unsigned)(sb * 16);
        gA[i] = Xb + (size_t)(bi + row) * 256 + kq * 16;
        gB[i] = Yb + (size_t)(bj + row) * 256 + kq * 16;
    }

    floatx16 acc[2][2];
    #pragma unroll
    for (int i = 0; i < 2; i++)
        #pragma unroll
        for (int j = 0; j < 2; j++)
            #pragma unroll
            for (int r = 0; r < 16; r++)
                acc[i][j][r] = -SC20L2E;

    #pragma unroll
    for (int ph = 0; ph < 2; ph++) {
        if (ph) __syncthreads();        // phase-0 LDS reads complete
        int ko = ph * 128;
        #pragma unroll
        for (int i = 0; i < 4; i++) {
            async_cp16(smem + ldsoff[i],         gA[i] + ko);
            async_cp16(smem + 16384 + ldsoff[i], gB[i] + ko);
        }
        __syncthreads();                // staging drained (vmcnt in barrier)

        #pragma unroll 1                // cap fragment liveness (no spill)
        for (int ks = 0; ks < 2; ks++) {
            const unsigned kx = (unsigned)(ks << 6);
            intx8 A[2], B[2];
            #pragma unroll
            for (int t = 0; t < 2; t++) {
                unsigned a0 = qa[t] ^ kx;
                intx4 lo = *(const intx4*)(smem + a0);
                intx4 hi = *(const intx4*)(smem + (a0 ^ 16u));
                A[t] = (intx8){lo[0], lo[1], lo[2], lo[3], hi[0], hi[1], hi[2], hi[3]};
                unsigned b0 = qb2[t] ^ kx;
                intx4 bl = *(const intx4*)(smem + b0);
                intx4 bh = *(const intx4*)(smem + (b0 ^ 16u));
                B[t] = (intx8){bl[0], bl[1], bl[2], bl[3], bh[0], bh[1], bh[2], bh[3]};
            }
            #pragma unroll
            for (int i = 0; i < 2; i++)
                #pragma unroll
                for (int j = 0; j < 2; j++)
                    acc[i][j] = __builtin_amdgcn_mfma_scale_f32_32x32x64_f8f6f4(
                        A[i], B[j], acc[i][j], 0, 0,
                        0, 0x7F7F7F7F, 0, 0x7F7F7F7F);
        }
    }

    // ---- epilogue: exp2 (raw v_exp_f32), butterfly reductions, atomics ----
    #pragma unroll
    for (int i = 0; i < 2; i++)
        #pragma unroll
        for (int j = 0; j < 2; j++)
            #pragma unroll
            for (int r = 0; r < 16; r++)
                acc[i][j][r] = EXP2F(acc[i][j][r]);

    // Row sums: v[t], t = ti*16 + reg, reduced over the 32 l5-lanes via
    // 5-level value-splitting butterfly; lane l5 ends holding v[l5].
    float v[32];
    #pragma unroll
    for (int t = 0; t < 2; t++)
        #pragma unroll
        for (int r = 0; r < 16; r++)
            v[t * 16 + r] = acc[t][0][r] + acc[t][1][r];

    float u1[16];
    #pragma unroll
    for (int k = 0; k < 16; k++) {
        float snd = (l5 & 1) ? v[2 * k] : v[2 * k + 1];
        float got = __shfl_xor(snd, 1, 64);
        u1[k] = ((l5 & 1) ? v[2 * k + 1] : v[2 * k]) + got;
    }
    float u2[8];
    #pragma unroll
    for (int k = 0; k < 8; k++) {
        float snd = ((l5 >> 1) & 1) ? u1[2 * k] : u1[2 * k + 1];
        float got = __shfl_xor(snd, 2, 64);
        u2[k] = (((l5 >> 1) & 1) ? u1[2 * k + 1] : u1[2 * k]) + got;
    }
    float u3[4];
    #pragma unroll
    for (int k = 0; k < 4; k++) {
        float snd = ((l5 >> 2) & 1) ? u2[2 * k] : u2[2 * k + 1];
        float got = __shfl_xor(snd, 4, 64);
        u3[k] = (((l5 >> 2) & 1) ? u2[2 * k + 1] : u2[2 * k]) + got;
    }
    float u4[2];
    #pragma unroll
    for (int k = 0; k < 2; k++) {
        float snd = ((l5 >> 3) & 1) ? u3[2 * k] : u3[2 * k + 1];
        float got = __shfl_xor(snd, 8, 64);
        u4[k] = (((l5 >> 3) & 1) ? u3[2 * k + 1] : u3[2 * k]) + got;
    }
    {
        float snd = ((l5 >> 4) & 1) ? u4[0] : u4[1];
        float got = __shfl_xor(snd, 16, 64);
        float wr = (((l5 >> 4) & 1) ? u4[1] : u4[0]) + got;
        // lane l5 holds row-sum for t=l5: ti = l5>>4, reg = l5&15
        int reg = l5 & 15;
        int row = bi + wm * 64 + (l5 >> 4) * 32
                + (reg & 3) + 8 * (reg >> 2) + 4 * h;
        atomicAdd(&rs[row], wr);
    }

    // Col sums: c[tj] = sum over both ti tiles' 16 regs; reduce over the two
    // h-halves (xor 32); lane ends holding the col-sum for tj = h.
    float c0 = 0.f, c1 = 0.f;
    #pragma unroll
    for (int t = 0; t < 2; t++)
        #pragma unroll
        for (int r = 0; r < 16; r++) {
            c0 += acc[t][0][r];
            c1 += acc[t][1][r];
        }
    {
        float snd = h ? c0 : c1;
        float got = __shfl_xor(snd, 32, 64);
        float cc = (h ? c1 : c0) + got;
        atomicAdd(&cs[bj + wn * 64 + h * 32 + l5], cc);
    }
}

// 64 blocks: each thread one (pair,row) entry; wave-reduce then atomicAdd
// into out (prep pre-set out = 40, the 20*4B/(2B) constant).
__global__ __launch_bounds__(256)
void final_reduce_kernel(const float* __restrict__ rowsum,
                         const float* __restrict__ colsum,
                         const float* __restrict__ diag,
                         float* __restrict__ out) {
    int idx = blockIdx.x * 256 + threadIdx.x;
    float acc = 0.5f * (__logf(rowsum[idx]) + __logf(colsum[idx])) - diag[idx];
    #pragma unroll
    for (int s = 32; s; s >>= 1) acc += __shfl_xor(acc, s, 64);
    if ((threadIdx.x & 63) == 0)
        atomicAdd(out, acc * (1.0f / (2.0f * BSZ)));
}

extern "C" void kernel_launch(void* const* d_in, const int* in_sizes, int n_in,
                              void* d_out, int out_size, void* d_ws, size_t ws_size,
                              hipStream_t stream) {
    const float* in_anchor = (const float*)d_in[0];
    const float* in_pos    = (const float*)d_in[1];
    // d_in[2] (reference_anchor) intentionally unused, matching the reference.
    const float* in_rtext  = (const float*)d_in[3];
    const float* in_rvis   = (const float*)d_in[4];

    char* ws = (char*)d_ws;
    unsigned char* f8 = (unsigned char*)ws;                 // 4 * B * D fp8
    size_t f8_bytes = (size_t)4 * BSZ * DIM;
    float* rowsum = (float*)(ws + f8_bytes);                // 4 * B
    float* colsum = rowsum + 4 * BSZ;                       // 4 * B
    float* diag   = colsum + 4 * BSZ;                       // 4 * B

    prep_kernel<<<BSZ / 4, 256, 0, stream>>>(
        in_anchor, in_pos, in_rtext, in_rvis, f8, diag, rowsum, colsum,
        (float*)d_out);

    pair_scores_kernel<<<dim3(BSZ / 128, BSZ / 128, 4), 256, 0, stream>>>(
        f8, rowsum, colsum);

    final_reduce_kernel<<<64, 256, 0, stream>>>(
        rowsum, colsum, diag, (float*)d_out);
}